// Round 1
// baseline (3551.077 us; speedup 1.0000x reference)
//
#include <hip/hip_runtime.h>
#include <math.h>

#define BB 64
#define CC 768
#define NN 1024
#define NB 4
#define BS 192
#define EPS 1e-5f
#define LAM 0.01f

// ---------------------------------------------------------------------------
// Kernel 1: LayerNorm statistics per (b, n): mean/rstd over channel dim.
// x layout: (B, C, N) with N contiguous. 256 thr = 4 c-lanes x 64 n-lanes.
// ---------------------------------------------------------------------------
__global__ void ln_stats(const float* __restrict__ x,
                         float* __restrict__ mu, float* __restrict__ rstd) {
    int tn = threadIdx.x & 63, tc = threadIdx.x >> 6;
    int n = blockIdx.x * 64 + tn, b = blockIdx.y;
    const float* xp = x + (size_t)b * CC * NN + n;
    float s = 0.f, ss = 0.f;
    for (int c = tc; c < CC; c += 4) {
        float v = xp[(size_t)c * NN];
        s += v; ss += v * v;
    }
    __shared__ float sm[4][64], sq[4][64];
    sm[tc][tn] = s; sq[tc][tn] = ss;
    __syncthreads();
    if (tc == 0) {
        s  = sm[0][tn] + sm[1][tn] + sm[2][tn] + sm[3][tn];
        ss = sq[0][tn] + sq[1][tn] + sq[2][tn] + sq[3][tn];
        float m = s * (1.f / 768.f);
        float v = ss * (1.f / 768.f) - m * m;
        mu[b * NN + n] = m;
        rstd[b * NN + n] = rsqrtf(v + EPS);
    }
}

// ---------------------------------------------------------------------------
// Kernel 2: fused LN-apply + 1024-pt DIF FFT over n (x4 signals, q=0..3)
// + 4-pt DFT over q + ortho scale (1/64). Output bit-reversed in n (OK:
// per-frequency MLP is n-order agnostic). One block per (d, b).
// ---------------------------------------------------------------------------
__global__ void fwd_fft(const float* __restrict__ x,
                        const float* __restrict__ mu_, const float* __restrict__ rs_,
                        const float* __restrict__ gamma, const float* __restrict__ beta,
                        float* __restrict__ Xr, float* __restrict__ Xi) {
    __shared__ float re[4][1024], im[4][1024];
    int d = blockIdx.x, b = blockIdx.y, tid = threadIdx.x;

    const float* mp = mu_ + b * NN;
    const float* rp = rs_ + b * NN;
    for (int q = 0; q < 4; q++) {
        int c = q * BS + d;
        float g = gamma[c], be = beta[c];
        const float* xp = x + ((size_t)b * CC + c) * NN;
        for (int n = tid; n < NN; n += 256) {
            re[q][n] = (xp[n] - mp[n]) * rp[n] * g + be;
            im[q][n] = 0.f;
        }
    }
    __syncthreads();

    // radix-2 DIF, natural in -> bit-reversed out, twiddle e^{-i pi j/len}
    for (int len = 512; len >= 1; len >>= 1) {
        for (int t = tid; t < 512; t += 256) {
            int j = t & (len - 1);
            int i0 = ((t - j) << 1) + j;
            int i1 = i0 + len;
            float ang = -(float)M_PI * (float)j / (float)len;
            float sw, cw;
            sincosf(ang, &sw, &cw);
            #pragma unroll
            for (int q = 0; q < 4; q++) {
                float ar = re[q][i0], ai = im[q][i0];
                float br = re[q][i1], bi = im[q][i1];
                re[q][i0] = ar + br; im[q][i0] = ai + bi;
                float dr = ar - br, di = ai - bi;
                re[q][i1] = dr * cw - di * sw;
                im[q][i1] = dr * sw + di * cw;
            }
        }
        __syncthreads();
    }

    // 4-point DFT across q (in order!), scale 1/64, store
    const float sc = 1.f / 64.f;
    for (int n = tid; n < NN; n += 256) {
        float x0r = re[0][n], x0i = im[0][n];
        float x1r = re[1][n], x1i = im[1][n];
        float x2r = re[2][n], x2i = im[2][n];
        float x3r = re[3][n], x3i = im[3][n];
        float X0r = x0r + x1r + x2r + x3r, X0i = x0i + x1i + x2i + x3i;
        float X2r = x0r - x1r + x2r - x3r, X2i = x0i - x1i + x2i - x3i;
        float X1r = x0r + x1i - x2r - x3i, X1i = x0i - x1r - x2i + x3r;
        float X3r = x0r - x1i - x2r + x3i, X3i = x0i + x1r - x2i - x3r;
        size_t base = (((size_t)b * 4) * BS + d) * NN + n;
        size_t qs = (size_t)BS * NN;
        Xr[base]          = X0r * sc; Xi[base]          = X0i * sc;
        Xr[base + qs]     = X1r * sc; Xi[base + qs]     = X1i * sc;
        Xr[base + 2 * qs] = X2r * sc; Xi[base + 2 * qs] = X2i * sc;
        Xr[base + 3 * qs] = X3r * sc; Xi[base + 3 * qs] = X3i * sc;
    }
}

// ---------------------------------------------------------------------------
// Kernel 3: per-frequency complex 2-layer block MLP, in-place on (Xr, Xi).
// Block = (n-tile of 16, q, b); 192 threads, thread = output column k.
// LDS: X tile and hidden tile as float2 (re,im), padded to kill conflicts.
// ---------------------------------------------------------------------------
__global__ __launch_bounds__(192) void mlp(const float* __restrict__ w1,
                                           const float* __restrict__ w2,
                                           const float* __restrict__ b1,
                                           const float* __restrict__ b2,
                                           float* __restrict__ Xr,
                                           float* __restrict__ Xi) {
    int n0 = blockIdx.x * 16, q = blockIdx.y, b = blockIdx.z;
    int k = threadIdx.x;  // 0..191
    __shared__ float2 sX[BS][17];
    __shared__ float2 sH[BS][17];

    size_t rbase = (((size_t)b * 4 + q) * BS + k) * NN + n0;
    #pragma unroll
    for (int j = 0; j < 16; j++)
        sX[k][j] = make_float2(Xr[rbase + j], Xi[rbase + j]);
    __syncthreads();

    float hr[16], hi[16];
    #pragma unroll
    for (int j = 0; j < 16; j++) { hr[j] = 0.f; hi[j] = 0.f; }

    const float* w1r = w1 + (size_t)q * BS * BS + k;
    const float* w1i = w1 + ((size_t)4 + q) * BS * BS + k;
    for (int d = 0; d < BS; d++) {
        float wr = w1r[(size_t)d * BS], wi = w1i[(size_t)d * BS];
        #pragma unroll
        for (int j = 0; j < 16; j++) {
            float2 xv = sX[d][j];
            hr[j] = fmaf(xv.x, wr, fmaf(-xv.y, wi, hr[j]));
            hi[j] = fmaf(xv.x, wi, fmaf( xv.y, wr, hi[j]));
        }
    }
    float br = b1[q * BS + k], bi = b1[(4 + q) * BS + k];
    #pragma unroll
    for (int j = 0; j < 16; j++) {
        hr[j] = fmaxf(hr[j] + br, 0.f);
        hi[j] = fmaxf(hi[j] + bi, 0.f);
        sH[k][j] = make_float2(hr[j], hi[j]);
    }
    __syncthreads();

    #pragma unroll
    for (int j = 0; j < 16; j++) { hr[j] = 0.f; hi[j] = 0.f; }
    const float* w2r = w2 + (size_t)q * BS * BS + k;
    const float* w2i = w2 + ((size_t)4 + q) * BS * BS + k;
    for (int d = 0; d < BS; d++) {
        float wr = w2r[(size_t)d * BS], wi = w2i[(size_t)d * BS];
        #pragma unroll
        for (int j = 0; j < 16; j++) {
            float2 hv = sH[d][j];
            hr[j] = fmaf(hv.x, wr, fmaf(-hv.y, wi, hr[j]));
            hi[j] = fmaf(hv.x, wi, fmaf( hv.y, wr, hi[j]));
        }
    }
    br = b2[q * BS + k]; bi = b2[(4 + q) * BS + k];
    #pragma unroll
    for (int j = 0; j < 16; j++) {
        float r2 = hr[j] + br, i2 = hi[j] + bi;
        r2 = (r2 > LAM) ? (r2 - LAM) : ((r2 < -LAM) ? (r2 + LAM) : 0.f);
        i2 = (i2 > LAM) ? (i2 - LAM) : ((i2 < -LAM) ? (i2 + LAM) : 0.f);
        Xr[rbase + j] = r2;
        Xi[rbase + j] = i2;
    }
}

// ---------------------------------------------------------------------------
// Kernel 4: inverse 4-pt DFT over q + 1024-pt DIT IFFT (bit-rev in, natural
// out, e^{+i} twiddles), real part * 1/64 + residual -> out.
// Yi lives in `out` (same indexing); in-place per block.
// ---------------------------------------------------------------------------
__global__ void inv_fft(const float* __restrict__ x,
                        const float* __restrict__ Yr,
                        float* __restrict__ out) {
    __shared__ float re[4][1024], im[4][1024];
    int d = blockIdx.x, b = blockIdx.y, tid = threadIdx.x;

    for (int q = 0; q < 4; q++) {
        size_t row = (((size_t)b * 4 + q) * BS + d) * NN;
        for (int n = tid; n < NN; n += 256) {
            re[q][n] = Yr[row + n];
            im[q][n] = out[row + n];
        }
    }
    __syncthreads();

    // inverse 4-pt DFT over q (e^{+i}), elementwise in n
    for (int n = tid; n < NN; n += 256) {
        float x0r = re[0][n], x0i = im[0][n];
        float x1r = re[1][n], x1i = im[1][n];
        float x2r = re[2][n], x2i = im[2][n];
        float x3r = re[3][n], x3i = im[3][n];
        float Y0r = x0r + x1r + x2r + x3r, Y0i = x0i + x1i + x2i + x3i;
        float Y2r = x0r - x1r + x2r - x3r, Y2i = x0i - x1i + x2i - x3i;
        float Y1r = x0r - x1i - x2r + x3i, Y1i = x0i + x1r - x2i - x3r;
        float Y3r = x0r + x1i - x2r - x3i, Y3i = x0i - x1r - x2i + x3r;
        re[0][n] = Y0r; im[0][n] = Y0i;
        re[1][n] = Y1r; im[1][n] = Y1i;
        re[2][n] = Y2r; im[2][n] = Y2i;
        re[3][n] = Y3r; im[3][n] = Y3i;
    }
    __syncthreads();

    // radix-2 DIT, bit-reversed in -> natural out, twiddle e^{+i pi j/len}
    for (int len = 1; len <= 512; len <<= 1) {
        for (int t = tid; t < 512; t += 256) {
            int j = t & (len - 1);
            int i0 = ((t - j) << 1) + j;
            int i1 = i0 + len;
            float ang = (float)M_PI * (float)j / (float)len;
            float sw, cw;
            sincosf(ang, &sw, &cw);
            #pragma unroll
            for (int q = 0; q < 4; q++) {
                float br = re[q][i1], bi = im[q][i1];
                float tr = br * cw - bi * sw;
                float ti = br * sw + bi * cw;
                float ar = re[q][i0], ai = im[q][i0];
                re[q][i1] = ar - tr; im[q][i1] = ai - ti;
                re[q][i0] = ar + tr; im[q][i0] = ai + ti;
            }
        }
        __syncthreads();
    }

    const float sc = 1.f / 64.f;
    for (int q = 0; q < 4; q++) {
        size_t row = (((size_t)b * 4 + q) * BS + d) * NN;  // == (b*768 + q*192 + d)*1024
        const float* xp = x + row;
        for (int n = tid; n < NN; n += 256) {
            out[row + n] = re[q][n] * sc + xp[n];
        }
    }
}

// ---------------------------------------------------------------------------
extern "C" void kernel_launch(void* const* d_in, const int* in_sizes, int n_in,
                              void* d_out, int out_size, void* d_ws, size_t ws_size,
                              hipStream_t stream) {
    const float* x     = (const float*)d_in[0];
    const float* w1    = (const float*)d_in[1];
    const float* w2    = (const float*)d_in[2];
    const float* b1    = (const float*)d_in[3];
    const float* b2    = (const float*)d_in[4];
    const float* gamma = (const float*)d_in[5];
    const float* beta  = (const float*)d_in[6];

    float* Xr   = (float*)d_ws;                       // B*C*N floats
    float* mu   = Xr + (size_t)BB * CC * NN;          // B*N
    float* rstd = mu + (size_t)BB * NN;               // B*N
    float* Xi   = (float*)d_out;                      // imag plane lives in out

    ln_stats<<<dim3(NN / 64, BB), 256, 0, stream>>>(x, mu, rstd);
    fwd_fft<<<dim3(BS, BB), 256, 0, stream>>>(x, mu, rstd, gamma, beta, Xr, Xi);
    mlp<<<dim3(NN / 16, NB, BB), 192, 0, stream>>>(w1, w2, b1, b2, Xr, Xi);
    inv_fft<<<dim3(BS, BB), 256, 0, stream>>>(x, Xr, Xi);
}

// Round 2
// 1689.536 us; speedup vs baseline: 2.1018x; 2.1018x over previous
//
#include <hip/hip_runtime.h>
#include <math.h>

#define BB 64
#define CC 768
#define NN 1024
#define BS 192
#define EPS 1e-5f
#define LAM 0.01f

typedef float  f32x4  __attribute__((ext_vector_type(4)));
typedef short  bf16x8 __attribute__((ext_vector_type(8)));

__device__ inline unsigned f2bf(float x) {
    unsigned u = __float_as_uint(x);
    u += 0x7fff + ((u >> 16) & 1);   // RNE
    return u >> 16;
}
__device__ inline unsigned pack2(float r, float i) { return f2bf(r) | (f2bf(i) << 16); }
__device__ inline float bflo(unsigned v) { return __uint_as_float(v << 16); }
__device__ inline float bfhi(unsigned v) { return __uint_as_float(v & 0xffff0000u); }

// ---------------------------------------------------------------------------
// Kernel 1: LayerNorm statistics per (b, n).
// ---------------------------------------------------------------------------
__global__ void ln_stats(const float* __restrict__ x,
                         float* __restrict__ mu, float* __restrict__ rstd) {
    int tn = threadIdx.x & 63, tc = threadIdx.x >> 6;
    int n = blockIdx.x * 64 + tn, b = blockIdx.y;
    const float* xp = x + (size_t)b * CC * NN + n;
    float s = 0.f, ss = 0.f;
    for (int c = tc; c < CC; c += 4) {
        float v = xp[(size_t)c * NN];
        s += v; ss += v * v;
    }
    __shared__ float sm[4][64], sq[4][64];
    sm[tc][tn] = s; sq[tc][tn] = ss;
    __syncthreads();
    if (tc == 0) {
        s  = sm[0][tn] + sm[1][tn] + sm[2][tn] + sm[3][tn];
        ss = sq[0][tn] + sq[1][tn] + sq[2][tn] + sq[3][tn];
        float m = s * (1.f / 768.f);
        float v = ss * (1.f / 768.f) - m * m;
        mu[b * NN + n] = m;
        rstd[b * NN + n] = rsqrtf(v + EPS);
    }
}

// ---------------------------------------------------------------------------
// Kernel 2: LN-apply + 1024-pt DIF FFT (n) + 4-pt DFT (q) + 1/64 scale.
// Output: packed bf16 complex planes Xp[(b*4+q)*192 + d][n], dword=(re|im<<16).
// n is bit-reversed (MLP is n-order agnostic; inverse undoes it).
// ---------------------------------------------------------------------------
__global__ void fwd_fft(const float* __restrict__ x,
                        const float* __restrict__ mu_, const float* __restrict__ rs_,
                        const float* __restrict__ gamma, const float* __restrict__ beta,
                        unsigned* __restrict__ Xp) {
    __shared__ float re[4][1024], im[4][1024];
    int d = blockIdx.x, b = blockIdx.y, tid = threadIdx.x;

    const float* mp = mu_ + b * NN;
    const float* rp = rs_ + b * NN;
    for (int q = 0; q < 4; q++) {
        int c = q * BS + d;
        float g = gamma[c], be = beta[c];
        const float* xp = x + ((size_t)b * CC + c) * NN;
        for (int n = tid; n < NN; n += 256) {
            re[q][n] = (xp[n] - mp[n]) * rp[n] * g + be;
            im[q][n] = 0.f;
        }
    }
    __syncthreads();

    for (int len = 512; len >= 1; len >>= 1) {
        for (int t = tid; t < 512; t += 256) {
            int j = t & (len - 1);
            int i0 = ((t - j) << 1) + j;
            int i1 = i0 + len;
            float ang = -(float)M_PI * (float)j / (float)len;
            float sw, cw;
            sincosf(ang, &sw, &cw);
            #pragma unroll
            for (int q = 0; q < 4; q++) {
                float ar = re[q][i0], ai = im[q][i0];
                float br = re[q][i1], bi = im[q][i1];
                re[q][i0] = ar + br; im[q][i0] = ai + bi;
                float dr = ar - br, di = ai - bi;
                re[q][i1] = dr * cw - di * sw;
                im[q][i1] = dr * sw + di * cw;
            }
        }
        __syncthreads();
    }

    const float sc = 1.f / 64.f;
    for (int n = tid; n < NN; n += 256) {
        float x0r = re[0][n], x0i = im[0][n];
        float x1r = re[1][n], x1i = im[1][n];
        float x2r = re[2][n], x2i = im[2][n];
        float x3r = re[3][n], x3i = im[3][n];
        float X0r = x0r + x1r + x2r + x3r, X0i = x0i + x1i + x2i + x3i;
        float X2r = x0r - x1r + x2r - x3r, X2i = x0i - x1i + x2i - x3i;
        float X1r = x0r + x1i - x2r - x3i, X1i = x0i - x1r - x2i + x3r;
        float X3r = x0r - x1i - x2r + x3i, X3i = x0i + x1r - x2i - x3r;
        size_t base = (((size_t)b * 4) * BS + d) * NN + n;
        size_t qs = (size_t)BS * NN;
        Xp[base]          = pack2(X0r * sc, X0i * sc);
        Xp[base + qs]     = pack2(X1r * sc, X1i * sc);
        Xp[base + 2 * qs] = pack2(X2r * sc, X2i * sc);
        Xp[base + 3 * qs] = pack2(X3r * sc, X3i * sc);
    }
}

// ---------------------------------------------------------------------------
// Kernel 3: bf16 MFMA GEMM for one complex MLP layer, planes->planes.
// A: packed planes [bq][192][1024]; effective real A[m=n][k], k=2d -> re, 2d+1 -> im.
// B built on-the-fly from fp32 weights: [[Wr,Wi],[-Wi,Wr]] in interleaved (k,j).
// Tile 128(M) x 128(J), K chunks of 32 (16 d-pairs), 4 waves x (4x4) 16x16x32.
// Epilogue: bias + activation -> bf16, LDS-transposed, coalesced plane stores.
// ACT 0: ReLU (layer1), 1: softshrink (layer2).
// ---------------------------------------------------------------------------
template <int ACT>
__global__ __launch_bounds__(256) void gemm_mlp(const unsigned* __restrict__ Ap,
                                                const float* __restrict__ w,
                                                const float* __restrict__ bias,
                                                unsigned* __restrict__ Cp) {
    // LDS rows: 32 bf16 (16 k-pair dwords) + pad to 40 shorts (80 B, 16B-aligned)
    __shared__ union {
        struct { unsigned short a[128 * 40]; unsigned short b[128 * 40]; } st;
        float cbuf[32 * 132];  // epilogue: 32 h-rows x 128 m dwords (+4 pad)
    } sm;

    const int mblk = blockIdx.x;   // 0..7   (m = n-dim, 128 per block)
    const int nblk = blockIdx.y;   // 0..2   (j-dim, 128 per block)
    const int bq   = blockIdx.z;   // 0..255
    const int q    = bq & 3;
    const int tid  = threadIdx.x;
    const int wave = tid >> 6;
    const int lane = tid & 63;
    const int l15  = lane & 15;
    const int quad = lane >> 4;
    const int wm   = (wave & 1) * 64;
    const int wn   = (wave >> 1) * 64;

    // A staging: thread = (d-row ar, 8 m-dwords at am)
    const int ar = tid >> 4;
    const int am = (tid & 15) * 8;
    const unsigned* arow_base = Ap + ((size_t)bq * BS) * NN + mblk * 128 + am;

    const float* wr_base = w + ((size_t)q * BS) * BS;
    const float* wi_base = w + ((size_t)(4 + q) * BS) * BS;

    f32x4 acc[4][4];
    #pragma unroll
    for (int i = 0; i < 4; i++)
        #pragma unroll
        for (int j = 0; j < 4; j++)
            acc[i][j] = (f32x4)0.f;

    unsigned* a32 = (unsigned*)sm.st.a;
    unsigned* b32 = (unsigned*)sm.st.b;

    for (int ch = 0; ch < 12; ch++) {
        __syncthreads();
        // --- stage A (transpose plane row -> [m][kpair]) ---
        {
            const unsigned* g = arow_base + (size_t)(ch * 16 + ar) * NN;
            uint4 v0 = *(const uint4*)g;
            uint4 v1 = *(const uint4*)(g + 4);
            a32[(am + 0) * 20 + ar] = v0.x;
            a32[(am + 1) * 20 + ar] = v0.y;
            a32[(am + 2) * 20 + ar] = v0.z;
            a32[(am + 3) * 20 + ar] = v0.w;
            a32[(am + 4) * 20 + ar] = v1.x;
            a32[(am + 5) * 20 + ar] = v1.y;
            a32[(am + 6) * 20 + ar] = v1.z;
            a32[(am + 7) * 20 + ar] = v1.w;
        }
        // --- stage B from fp32 weights ---
        #pragma unroll
        for (int rep = 0; rep < 4; rep++) {
            int idx = rep * 256 + tid;
            int h = idx & 63, dd = idx >> 6;          // h: 0..63, dd: 0..15
            int hg = nblk * 64 + h, dg = ch * 16 + dd;
            float Wr = wr_base[(size_t)dg * BS + hg];
            float Wi = wi_base[(size_t)dg * BS + hg];
            b32[(2 * h) * 20 + dd]     = pack2(Wr, -Wi);  // j even: Hr column
            b32[(2 * h + 1) * 20 + dd] = pack2(Wi,  Wr);  // j odd:  Hi column
        }
        __syncthreads();
        // --- fragments + MFMA ---
        bf16x8 af[4], bfr[4];
        #pragma unroll
        for (int t = 0; t < 4; t++) {
            af[t]  = *(const bf16x8*)((const char*)sm.st.a + (wm + t * 16 + l15) * 80 + quad * 16);
            bfr[t] = *(const bf16x8*)((const char*)sm.st.b + (wn + t * 16 + l15) * 80 + quad * 16);
        }
        #pragma unroll
        for (int tm = 0; tm < 4; tm++)
            #pragma unroll
            for (int tn = 0; tn < 4; tn++)
                acc[tm][tn] = __builtin_amdgcn_mfma_f32_16x16x32_bf16(af[tm], bfr[tn], acc[tm][tn], 0, 0, 0);
    }

    // --- epilogue: bias + act -> bf16, LDS transpose, coalesced plane stores ---
    for (int p = 0; p < 2; p++) {
        __syncthreads();
        if ((wave >> 1) == p) {
            #pragma unroll
            for (int tn = 0; tn < 4; tn++) {
                int jl = wn + tn * 16 + l15;          // p*64 .. p*64+63
                int jg = nblk * 128 + jl;
                int e = jg & 1, hg = jg >> 1;
                float bv = bias[e * 768 + q * BS + hg];
                int hh = (jl - p * 64) >> 1;          // 0..31
                #pragma unroll
                for (int tm = 0; tm < 4; tm++) {
                    #pragma unroll
                    for (int r = 0; r < 4; r++) {
                        int ml = wm + tm * 16 + quad * 4 + r;
                        float v = acc[tm][tn][r] + bv;
                        if (ACT == 0) v = fmaxf(v, 0.f);
                        else v = (v > LAM) ? (v - LAM) : ((v < -LAM) ? (v + LAM) : 0.f);
                        ((unsigned short*)sm.cbuf)[hh * 264 + ml * 2 + e] = (unsigned short)f2bf(v);
                    }
                }
            }
        }
        __syncthreads();
        {
            int hh = tid >> 3, seg = tid & 7;
            const uint4* src = (const uint4*)((const char*)sm.cbuf + hh * 528 + seg * 64);
            int hgrow = nblk * 64 + p * 32 + hh;
            uint4* dst = (uint4*)(Cp + ((size_t)bq * BS + hgrow) * NN + mblk * 128 + seg * 16);
            uint4 t0 = src[0], t1 = src[1], t2 = src[2], t3 = src[3];
            dst[0] = t0; dst[1] = t1; dst[2] = t2; dst[3] = t3;
        }
    }
}

// ---------------------------------------------------------------------------
// Kernel 4: inverse 4-pt DFT (q) + 1024-pt DIT IFFT + real*1/64 + residual.
// Reads packed bf16 complex planes Yp.
// ---------------------------------------------------------------------------
__global__ void inv_fft(const float* __restrict__ x,
                        const unsigned* __restrict__ Yp,
                        float* __restrict__ out) {
    __shared__ float re[4][1024], im[4][1024];
    int d = blockIdx.x, b = blockIdx.y, tid = threadIdx.x;

    for (int q = 0; q < 4; q++) {
        size_t row = (((size_t)b * 4 + q) * BS + d) * NN;
        for (int n = tid; n < NN; n += 256) {
            unsigned v = Yp[row + n];
            re[q][n] = bflo(v);
            im[q][n] = bfhi(v);
        }
    }
    __syncthreads();

    for (int n = tid; n < NN; n += 256) {
        float x0r = re[0][n], x0i = im[0][n];
        float x1r = re[1][n], x1i = im[1][n];
        float x2r = re[2][n], x2i = im[2][n];
        float x3r = re[3][n], x3i = im[3][n];
        float Y0r = x0r + x1r + x2r + x3r, Y0i = x0i + x1i + x2i + x3i;
        float Y2r = x0r - x1r + x2r - x3r, Y2i = x0i - x1i + x2i - x3i;
        float Y1r = x0r - x1i - x2r + x3i, Y1i = x0i + x1r - x2i - x3r;
        float Y3r = x0r + x1i - x2r - x3i, Y3i = x0i - x1r - x2i + x3r;
        re[0][n] = Y0r; im[0][n] = Y0i;
        re[1][n] = Y1r; im[1][n] = Y1i;
        re[2][n] = Y2r; im[2][n] = Y2i;
        re[3][n] = Y3r; im[3][n] = Y3i;
    }
    __syncthreads();

    for (int len = 1; len <= 512; len <<= 1) {
        for (int t = tid; t < 512; t += 256) {
            int j = t & (len - 1);
            int i0 = ((t - j) << 1) + j;
            int i1 = i0 + len;
            float ang = (float)M_PI * (float)j / (float)len;
            float sw, cw;
            sincosf(ang, &sw, &cw);
            #pragma unroll
            for (int q = 0; q < 4; q++) {
                float br = re[q][i1], bi = im[q][i1];
                float tr = br * cw - bi * sw;
                float ti = br * sw + bi * cw;
                float ar = re[q][i0], ai = im[q][i0];
                re[q][i1] = ar - tr; im[q][i1] = ai - ti;
                re[q][i0] = ar + tr; im[q][i0] = ai + ti;
            }
        }
        __syncthreads();
    }

    const float sc = 1.f / 64.f;
    for (int q = 0; q < 4; q++) {
        size_t row = (((size_t)b * 4 + q) * BS + d) * NN;
        const float* xp = x + row;
        for (int n = tid; n < NN; n += 256) {
            out[row + n] = re[q][n] * sc + xp[n];
        }
    }
}

// ---------------------------------------------------------------------------
extern "C" void kernel_launch(void* const* d_in, const int* in_sizes, int n_in,
                              void* d_out, int out_size, void* d_ws, size_t ws_size,
                              hipStream_t stream) {
    const float* x     = (const float*)d_in[0];
    const float* w1    = (const float*)d_in[1];
    const float* w2    = (const float*)d_in[2];
    const float* b1    = (const float*)d_in[3];
    const float* b2    = (const float*)d_in[4];
    const float* gamma = (const float*)d_in[5];
    const float* beta  = (const float*)d_in[6];

    unsigned* Xp = (unsigned*)d_ws;                       // packed bf16 complex planes
    float* mu    = (float*)d_ws + (size_t)BB * CC * NN;   // after 50.3M dwords
    float* rstd  = mu + (size_t)BB * NN;
    unsigned* Hp = (unsigned*)d_out;                      // H planes alias d_out
    unsigned* Yp = Xp;                                    // Y reuses X region

    ln_stats<<<dim3(NN / 64, BB), 256, 0, stream>>>(x, mu, rstd);
    fwd_fft<<<dim3(BS, BB), 256, 0, stream>>>(x, mu, rstd, gamma, beta, Xp);
    gemm_mlp<0><<<dim3(8, 3, 256), 256, 0, stream>>>(Xp, w1, b1, Hp);
    gemm_mlp<1><<<dim3(8, 3, 256), 256, 0, stream>>>(Hp, w2, b2, Yp);
    inv_fft<<<dim3(BS, BB), 256, 0, stream>>>(x, Yp, (float*)d_out);
}